// Round 5
// baseline (803.332 us; speedup 1.0000x reference)
//
#include <hip/hip_runtime.h>
#include <cstdint>
#include <cstddef>

// ---------------- problem constants ----------------
#define D_N     1024
#define K_S     128
#define EDIM    384
#define HID     128
#define NHEAD   4
#define HDIM    32
#define FFD     128
#define NLAYER  2
#define ETOT    (D_N * K_S)
#define NNODES  200000
#define NBINS   (2 * D_N + 2)
#define NCH     512
#define CHL     (ETOT / NCH)

// ---------------- workspace layout (bytes) ----------------
#define OFF_ORDER 0u
#define OFF_KEY   0x080000u
#define OFF_SLOT  0x100000u
#define OFF_HIST  0x200000u                 // 2050*512*4 = 4,198,400
#define OFF_TOT   0x601800u                 // 8,200 B
#define OFF_WBF   0x604000u                 // 491,520 B (own region now)
#define OFF_POOL  0x680000u                 // 512 KB
#define WP_OFF 0
#define WI_OFF 49152
#define WO_OFF 147456
#define W1_OFF 180224
#define W2_OFF 212992
#define WTOT   245760

typedef __attribute__((ext_vector_type(8))) short  bf16x8;
typedef __attribute__((ext_vector_type(4))) short  short4v;
typedef __attribute__((ext_vector_type(4))) float  f32x4;

__device__ __forceinline__ short f2bf(float f) {
    union { float f; unsigned u; } v; v.f = f;
    unsigned r = v.u + 0x7fffu + ((v.u >> 16) & 1u);
    return (short)(r >> 16);
}
__device__ __forceinline__ int swz_off(int r, int byteInRow, int strideBytes) {
    return (r * strideBytes + byteInRow) ^ ((r & 7) << 4);
}

// ============================================================
// preprocessing
// ============================================================
__global__ void init_cvt(int* __restrict__ slot, int* __restrict__ hist,
                         const float* __restrict__ p0, const float* __restrict__ p1,
                         const float* __restrict__ p2, const float* __restrict__ p3,
                         const float* __restrict__ p4, short* __restrict__ wbf)
{
    int idx = blockIdx.x * blockDim.x + threadIdx.x;
    int stride = gridDim.x * blockDim.x;
    for (int i = idx; i < NBINS * NCH; i += stride) hist[i] = 0;
    for (int i = idx; i < NNODES; i += stride) slot[i] = D_N;
    int i = idx * 8;
    if (i < WTOT) {
        const float* s;
        if      (i < WI_OFF) s = p0 + i;
        else if (i < WO_OFF) s = p1 + (i - WI_OFF);
        else if (i < W1_OFF) s = p2 + (i - WO_OFF);
        else if (i < W2_OFF) s = p3 + (i - W1_OFF);
        else                 s = p4 + (i - W2_OFF);
        float4 a = *(const float4*)s;
        float4 b = *(const float4*)(s + 4);
        bf16x8 o;
        o[0] = f2bf(a.x); o[1] = f2bf(a.y); o[2] = f2bf(a.z); o[3] = f2bf(a.w);
        o[4] = f2bf(b.x); o[5] = f2bf(b.y); o[6] = f2bf(b.z); o[7] = f2bf(b.w);
        *(bf16x8*)(wbf + i) = o;
    }
}

__global__ void find_neigh(const int* __restrict__ eidx,
                           const int* __restrict__ tgt_idx,
                           int* __restrict__ slot)
{
    __shared__ int wtot[16];
    __shared__ int wbase_s[16];
    __shared__ int neigh[D_N];
    const int tid  = threadIdx.x;          // 1024
    const int lane = tid & 63;
    const int wv   = tid >> 6;
    const int tgt  = tgt_idx[0];
    const int* src = eidx;
    const int* dst = eidx + ETOT;
    const int epc  = ETOT / 1024;          // 128
    const int e0   = tid * epc;

    int c = 0;
    const int4* s4 = (const int4*)(src + e0);
    #pragma unroll 8
    for (int i = 0; i < epc / 4; ++i) {
        int4 v = s4[i];
        c += (v.x == tgt) + (v.y == tgt) + (v.z == tgt) + (v.w == tgt);
    }
    int incl = c;
    #pragma unroll
    for (int d = 1; d < 64; d <<= 1) {
        int t = __shfl_up(incl, d, 64);
        if (lane >= d) incl += t;
    }
    if (lane == 63) wtot[wv] = incl;
    __syncthreads();
    if (tid < 16) {
        int s = 0;
        for (int j = 0; j < tid; ++j) s += wtot[j];
        wbase_s[tid] = s;
    }
    __syncthreads();
    int r = wbase_s[wv] + incl - c;
    for (int e = e0; e < e0 + epc; ++e) {
        if (src[e] == tgt) { if (r < D_N) neigh[r] = dst[e]; ++r; }
    }
    __syncthreads();
    int total = wbase_s[15] + wtot[15];
    if (tid < total && tid < D_N) slot[neigh[tid]] = tid;
}

__global__ void compute_key(const int* __restrict__ eidx,
                            const int* __restrict__ tgt_idx,
                            const int* __restrict__ slot,
                            int* __restrict__ key)
{
    int e = blockIdx.x * 256 + threadIdx.x;
    if (e >= ETOT) return;
    int tgt = tgt_idx[0];
    key[e] = slot[eidx[ETOT + e]] * 2 + ((eidx[e] != tgt) ? 1 : 0);
}

__global__ void hist_build(const int* __restrict__ key, int* __restrict__ hist)
{
    const int c = blockIdx.x * 256 + threadIdx.x;
    if (c >= NCH) return;
    const int4* kp = (const int4*)(key + c * CHL);
    int cur = -1, run = 0;
    for (int i = 0; i < CHL / 4; ++i) {
        int4 k4 = kp[i];
        #pragma unroll
        for (int j = 0; j < 4; ++j) {
            int k = (j == 0) ? k4.x : (j == 1) ? k4.y : (j == 2) ? k4.z : k4.w;
            if (k == cur) { ++run; }
            else {
                if (run) hist[cur * NCH + c] += run;
                cur = k; run = 1;
            }
        }
    }
    if (run) hist[cur * NCH + c] += run;
}

__global__ void scan_pass1(const int* __restrict__ hist, int* __restrict__ tot)
{
    int b = blockIdx.x * 256 + threadIdx.x;
    if (b >= NBINS) return;
    const int4* h = (const int4*)(hist + b * NCH);
    int s = 0;
    #pragma unroll 4
    for (int c = 0; c < NCH / 4; ++c) { int4 v = h[c]; s += v.x + v.y + v.z + v.w; }
    tot[b] = s;
}

#define SCN 2176
__global__ void scan_pass2(int* __restrict__ tot)
{
    __shared__ int A[SCN];
    __shared__ int B[SCN];
    const int tid = threadIdx.x;   // 1024
    for (int i = tid; i < SCN; i += 1024) A[i] = (i < NBINS) ? tot[i] : 0;
    __syncthreads();
    int* cur = A; int* nxt = B;
    for (int s = 1; s < SCN; s <<= 1) {
        for (int i = tid; i < SCN; i += 1024) nxt[i] = (i >= s) ? cur[i] + cur[i - s] : cur[i];
        __syncthreads();
        int* t = cur; cur = nxt; nxt = t;
    }
    for (int i = tid; i < NBINS; i += 1024) tot[i] = (i == 0) ? 0 : cur[i - 1];
}

__global__ void scan_pass3(int* __restrict__ hist, const int* __restrict__ base)
{
    const int wvg  = (blockIdx.x * blockDim.x + threadIdx.x) >> 6;
    const int lane = threadIdx.x & 63;
    if (wvg >= NBINS) return;
    int* h = hist + wvg * NCH + lane * 8;
    int4 a = *(int4*)h;
    int4 b4 = *(int4*)(h + 4);
    int ls = a.x + a.y + a.z + a.w + b4.x + b4.y + b4.z + b4.w;
    int incl = ls;
    #pragma unroll
    for (int d = 1; d < 64; d <<= 1) {
        int t = __shfl_up(incl, d, 64);
        if (lane >= d) incl += t;
    }
    int run = base[wvg] + incl - ls;
    int4 o1, o2;
    o1.x = run; run += a.x;  o1.y = run; run += a.y;
    o1.z = run; run += a.z;  o1.w = run; run += a.w;
    o2.x = run; run += b4.x; o2.y = run; run += b4.y;
    o2.z = run; run += b4.z; o2.w = run; run += b4.w;
    *(int4*)h = o1;
    *(int4*)(h + 4) = o2;
}

__global__ void scatter_order(const int* __restrict__ key,
                              int* __restrict__ hist,
                              int* __restrict__ order)
{
    const int c = blockIdx.x * 256 + threadIdx.x;
    if (c >= NCH) return;
    const int e0 = c * CHL;
    const int4* kp = (const int4*)(key + e0);
    int cur = -1, pos = 0;
    for (int i = 0; i < CHL / 4; ++i) {
        int4 k4 = kp[i];
        #pragma unroll
        for (int j = 0; j < 4; ++j) {
            int k = (j == 0) ? k4.x : (j == 1) ? k4.y : (j == 2) ? k4.z : k4.w;
            if (k != cur) {
                if (cur >= 0) hist[cur * NCH + c] = pos;
                cur = k;
                pos = hist[k * NCH + c];
            }
            if (pos >= 0 && pos < ETOT) order[pos] = e0 + i * 4 + j;
            ++pos;
        }
    }
    if (cur >= 0) hist[cur * NCH + c] = pos;
}

// ============================================================
// MFMA tile helper: A from swizzled LDS (own 16 rows), B via functor.
// ============================================================
template<int CF, int KC, typename GetB>
__device__ __forceinline__ void gemm1(f32x4 (&acc)[CF],
    const char* aB, int aRow0, int aStride, int aColOff, int l15, int g, GetB getB)
{
    #pragma unroll
    for (int kc = 0; kc < KC; ++kc) {
        bf16x8 a = *(const bf16x8*)(aB +
            swz_off(aRow0 + l15, aColOff + kc * 64 + g * 16, aStride));
        #pragma unroll
        for (int cf = 0; cf < CF; ++cf)
            acc[cf] = __builtin_amdgcn_mfma_f32_16x16x32_bf16(a, getB(cf, kc), acc[cf], 0, 0, 0);
    }
}

__device__ __forceinline__ void layer_norm1(f32x4 (&x)[8],
    const float* __restrict__ gg, const float* __restrict__ bb, int l15)
{
    float gv[8], bv[8];
    #pragma unroll
    for (int cf = 0; cf < 8; ++cf) { gv[cf] = gg[l15 + 16 * cf]; bv[cf] = bb[l15 + 16 * cf]; }
    #pragma unroll
    for (int rg = 0; rg < 4; ++rg) {
        float s = 0.f;
        #pragma unroll
        for (int cf = 0; cf < 8; ++cf) s += x[cf][rg];
        s += __shfl_xor(s, 1); s += __shfl_xor(s, 2);
        s += __shfl_xor(s, 4); s += __shfl_xor(s, 8);
        float mean = s * (1.f / 128.f);
        float v = 0.f;
        #pragma unroll
        for (int cf = 0; cf < 8; ++cf) { float d = x[cf][rg] - mean; v += d * d; }
        v += __shfl_xor(v, 1); v += __shfl_xor(v, 2);
        v += __shfl_xor(v, 4); v += __shfl_xor(v, 8);
        float rs = rsqrtf(v * (1.f / 128.f) + 1e-5f);
        #pragma unroll
        for (int cf = 0; cf < 8; ++cf)
            x[cf][rg] = (x[cf][rg] - mean) * rs * gv[cf] + bv[cf];
    }
}

// ============================================================
// fused transformer: 1 block = 1 neighbor; 512 thr = 8 waves x 16 rows.
// LDS 80 KB -> 2 blocks/CU (4 waves/SIMD). B operands from L2.
// Head-pair schedule: 5 barriers/layer, FF phase barrier-free.
// ============================================================
#define LDS_TOTAL 81920
__global__ __launch_bounds__(512, 2) void fused_mfma(
    const float* __restrict__ edge_attrs,
    const float* __restrict__ ftm,
    const short* __restrict__ wP, const float* __restrict__ projb,
    const short* __restrict__ wI, const float* __restrict__ aib,
    const short* __restrict__ wO, const float* __restrict__ aob,
    const float* __restrict__ l1g, const float* __restrict__ l1b,
    const short* __restrict__ w1, const float* __restrict__ f1b,
    const short* __restrict__ w2, const float* __restrict__ f2b,
    const float* __restrict__ l2g, const float* __restrict__ l2b,
    const int*   __restrict__ order,
    float*       __restrict__ pooled)
{
    __shared__ __align__(16) char sm[LDS_TOTAL];
    char* hbf = sm;                 // 32 KB [128 tok][256 B] swz - residual (bf16)
    char* q01 = sm + 32768;         // 16 KB [128 tok][128 B]  q (2 heads); P/O overlay
    char* k01 = sm + 49152;         // 16 KB [128 tok][128 B]  k (2 heads)
    char* vT  = sm + 65536;         // 16 KB [64 dim][256 B]   v^T (2 heads)
    char* ebuf = sm + 32768;        // 32 KB overlay (q01+k01): proj / ff1 staging
    float* pool_s = (float*)(sm + 32768);

    const int tid  = threadIdx.x;
    const int w    = tid >> 6;
    const int l    = tid & 63;
    const int l15  = l & 15;
    const int g    = l >> 4;
    const int row0 = 16 * w;
    const int b    = blockIdx.x;

    f32x4 hx[8];

    // ---------------- proj: h = rows @ projW^T + b (+ marker) -------------
    {
        #pragma unroll
        for (int cf = 0; cf < 8; ++cf) {
            float bs = projb[l15 + 16 * cf];
            hx[cf] = (f32x4){bs, bs, bs, bs};
        }
        const int r_off = l >> 2;
        const int coff  = (l & 3) * 32;
        const int row   = row0 + r_off;
        const int rowIdx = order[b * K_S + row];
        const float* arow = edge_attrs + (size_t)rowIdx * EDIM;

        float4 v[8];
        #pragma unroll
        for (int j = 0; j < 8; ++j) v[j] = *(const float4*)(arow + coff + j * 4);

        #pragma unroll
        for (int ch = 0; ch < 3; ++ch) {
            #pragma unroll
            for (int j = 0; j < 4; ++j) {
                float4 a = v[2 * j], c = v[2 * j + 1];
                bf16x8 pk;
                pk[0] = f2bf(a.x); pk[1] = f2bf(a.y); pk[2] = f2bf(a.z); pk[3] = f2bf(a.w);
                pk[4] = f2bf(c.x); pk[5] = f2bf(c.y); pk[6] = f2bf(c.z); pk[7] = f2bf(c.w);
                *(bf16x8*)(ebuf + swz_off(row, coff * 2 + j * 16, 256)) = pk;
            }
            if (ch < 2) {
                #pragma unroll
                for (int j = 0; j < 8; ++j)
                    v[j] = *(const float4*)(arow + (ch + 1) * 128 + coff + j * 4);
            }
            gemm1<8, 4>(hx, ebuf, row0, 256, 0, l15, g,
                [&](int cf, int kc) {
                    return *(const bf16x8*)(wP +
                        (size_t)(l15 + 16 * cf) * EDIM + ch * 128 + kc * 32 + g * 8);
                });
        }
        if (w == 0 && g == 0) {
            #pragma unroll
            for (int cf = 0; cf < 8; ++cf) hx[cf][0] += ftm[l15 + 16 * cf];
        }
        #pragma unroll
        for (int cf = 0; cf < 8; ++cf)
            #pragma unroll
            for (int rg = 0; rg < 4; ++rg)
                *(short*)(hbf + swz_off(row0 + g * 4 + rg, (l15 + 16 * cf) * 2, 256)) =
                    f2bf(hx[cf][rg]);
    }
    __syncthreads();   // ebuf overlay released for q01/k01

    // ---------------- transformer layers ----------------------------------
    for (int ly = 0; ly < NLAYER; ++ly) {
        const short* WIl = wI + (size_t)ly * 3 * HID * HID;
        const float* bI  = aib + ly * 3 * HID;
        const short* WOl = wO + (size_t)ly * HID * HID;
        const float* bO  = aob + ly * HID;
        const short* W1l = w1 + (size_t)ly * FFD * HID;
        const float* b1  = f1b + ly * FFD;
        const short* W2l = w2 + (size_t)ly * HID * FFD;
        const float* b2v = f2b + ly * HID;

        // fold attn-out bias into residual accumulator
        #pragma unroll
        for (int cf = 0; cf < 8; ++cf) {
            float bs = bO[l15 + 16 * cf];
            #pragma unroll
            for (int rg = 0; rg < 4; ++rg) hx[cf][rg] += bs;
        }

        #pragma unroll
        for (int hp = 0; hp < 2; ++hp) {
            // ---- QKV for the two heads of this pair ----
            #pragma unroll
            for (int hh = 0; hh < 2; ++hh) {
                const int hd = hp * 2 + hh;
                f32x4 acc[6];
                #pragma unroll
                for (int cf = 0; cf < 6; ++cf) {
                    float bs = bI[(cf >> 1) * HID + hd * HDIM + l15 + 16 * (cf & 1)];
                    acc[cf] = (f32x4){bs, bs, bs, bs};
                }
                gemm1<6, 4>(acc, hbf, row0, 256, 0, l15, g,
                    [&](int cf, int kc) {
                        int colw = (cf >> 1) * HID + hd * HDIM + l15 + 16 * (cf & 1);
                        return *(const bf16x8*)(WIl + (size_t)colw * HID + kc * 32 + g * 8);
                    });
                #pragma unroll
                for (int cf = 0; cf < 2; ++cf) {
                    int dcol = hh * 64 + (l15 + 16 * cf) * 2;
                    #pragma unroll
                    for (int rg = 0; rg < 4; ++rg) {
                        int row = row0 + g * 4 + rg;
                        *(short*)(q01 + swz_off(row, dcol, 128)) = f2bf(acc[cf][rg]);
                        *(short*)(k01 + swz_off(row, dcol, 128)) = f2bf(acc[2 + cf][rg]);
                    }
                    short4v pv;
                    pv[0] = f2bf(acc[4 + cf][0]); pv[1] = f2bf(acc[4 + cf][1]);
                    pv[2] = f2bf(acc[4 + cf][2]); pv[3] = f2bf(acc[4 + cf][3]);
                    *(short4v*)(vT + swz_off(hh * 32 + l15 + 16 * cf,
                                             (row0 + g * 4) * 2, 256)) = pv;
                }
            }
            __syncthreads();   // q01/k01/vT visible to all waves

            // ---- attention for both heads (no internal barriers) ----
            #pragma unroll
            for (int hh = 0; hh < 2; ++hh) {
                const int hd = hp * 2 + hh;
                // S = Q K^T   (A: own q rows; B: k cols, cross-wave)
                f32x4 sc[8];
                #pragma unroll
                for (int cf = 0; cf < 8; ++cf) sc[cf] = (f32x4){0.f, 0.f, 0.f, 0.f};
                gemm1<8, 1>(sc, q01, row0, 128, hh * 64, l15, g,
                    [&](int cf, int kc) {
                        (void)kc;
                        return *(const bf16x8*)(k01 +
                            swz_off(l15 + 16 * cf, hh * 64 + g * 16, 128));
                    });

                // softmax over 128 ktok (regs + 4 shfl per row)
                const float SC_ = 0.17677669529663687f;   // 1/sqrt(32)
                float inv_s[4];
                #pragma unroll
                for (int rg = 0; rg < 4; ++rg) {
                    float mx = -1e30f;
                    #pragma unroll
                    for (int cf = 0; cf < 8; ++cf) {
                        sc[cf][rg] *= SC_;
                        mx = fmaxf(mx, sc[cf][rg]);
                    }
                    mx = fmaxf(mx, __shfl_xor(mx, 1)); mx = fmaxf(mx, __shfl_xor(mx, 2));
                    mx = fmaxf(mx, __shfl_xor(mx, 4)); mx = fmaxf(mx, __shfl_xor(mx, 8));
                    float sum = 0.f;
                    #pragma unroll
                    for (int cf = 0; cf < 8; ++cf) {
                        float e = __expf(sc[cf][rg] - mx);
                        sc[cf][rg] = e; sum += e;
                    }
                    sum += __shfl_xor(sum, 1); sum += __shfl_xor(sum, 2);
                    sum += __shfl_xor(sum, 4); sum += __shfl_xor(sum, 8);
                    inv_s[rg] = 1.f / sum;
                }

                // O = P V : P chunks overlay own (consumed) q rows, bytes hh*64..
                f32x4 ov[2];
                ov[0] = (f32x4){0.f, 0.f, 0.f, 0.f};
                ov[1] = (f32x4){0.f, 0.f, 0.f, 0.f};
                #pragma unroll
                for (int cc = 0; cc < 4; ++cc) {
                    #pragma unroll
                    for (int q = 0; q < 2; ++q) {
                        int cfi = 2 * cc + q;
                        #pragma unroll
                        for (int rg = 0; rg < 4; ++rg)
                            *(short*)(q01 + swz_off(row0 + g * 4 + rg,
                                hh * 64 + (l15 + 16 * q) * 2, 128)) =
                                f2bf(sc[cfi][rg] * inv_s[rg]);
                    }
                    gemm1<2, 1>(ov, q01, row0, 128, hh * 64, l15, g,
                        [&](int cf, int kc) {
                            (void)kc;
                            return *(const bf16x8*)(vT + swz_off(hh * 32 + l15 + 16 * cf,
                                                                 cc * 64 + g * 16, 256));
                        });
                }
                // O_head -> same own-row region, then out-proj accumulate into hx
                #pragma unroll
                for (int cf = 0; cf < 2; ++cf)
                    #pragma unroll
                    for (int rg = 0; rg < 4; ++rg)
                        *(short*)(q01 + swz_off(row0 + g * 4 + rg,
                            hh * 64 + (l15 + 16 * cf) * 2, 128)) = f2bf(ov[cf][rg]);
                gemm1<8, 1>(hx, q01, row0, 128, hh * 64, l15, g,
                    [&](int cf, int kc) {
                        (void)kc;
                        return *(const bf16x8*)(WOl +
                            (size_t)(l15 + 16 * cf) * HID + hd * HDIM + g * 8);
                    });
            }
            __syncthreads();   // release q01/k01/vT for next pair / FF overlay
        } // head pairs

        // ---- LN1 -> hbf (wave-local) ----
        layer_norm1(hx, l1g + ly * HID, l1b + ly * HID, l15);
        #pragma unroll
        for (int cf = 0; cf < 8; ++cf)
            #pragma unroll
            for (int rg = 0; rg < 4; ++rg)
                *(short*)(hbf + swz_off(row0 + g * 4 + rg, (l15 + 16 * cf) * 2, 256)) =
                    f2bf(hx[cf][rg]);

        // ---- FF1 (relu) -> ebuf overlay (wave-local, no barriers) ----
        f32x4 ff[8];
        #pragma unroll
        for (int cf = 0; cf < 8; ++cf) {
            float bs = b1[l15 + 16 * cf];
            ff[cf] = (f32x4){bs, bs, bs, bs};
        }
        gemm1<8, 4>(ff, hbf, row0, 256, 0, l15, g,
            [&](int cf, int kc) {
                return *(const bf16x8*)(W1l +
                    (size_t)(l15 + 16 * cf) * HID + kc * 32 + g * 8);
            });
        #pragma unroll
        for (int cf = 0; cf < 8; ++cf)
            #pragma unroll
            for (int rg = 0; rg < 4; ++rg)
                *(short*)(ebuf + swz_off(row0 + g * 4 + rg, (l15 + 16 * cf) * 2, 256)) =
                    f2bf(fmaxf(ff[cf][rg], 0.f));

        // ---- FF2 + residual + LN2 ----
        f32x4 yy[8];
        #pragma unroll
        for (int cf = 0; cf < 8; ++cf) {
            float bs = b2v[l15 + 16 * cf];
            yy[cf] = (f32x4){bs, bs, bs, bs};
        }
        gemm1<8, 4>(yy, ebuf, row0, 256, 0, l15, g,
            [&](int cf, int kc) {
                return *(const bf16x8*)(W2l +
                    (size_t)(l15 + 16 * cf) * FFD + kc * 32 + g * 8);
            });
        #pragma unroll
        for (int cf = 0; cf < 8; ++cf) yy[cf] += hx[cf];
        layer_norm1(yy, l2g + ly * HID, l2b + ly * HID, l15);
        #pragma unroll
        for (int cf = 0; cf < 8; ++cf) {
            hx[cf] = yy[cf];
            #pragma unroll
            for (int rg = 0; rg < 4; ++rg)
                *(short*)(hbf + swz_off(row0 + g * 4 + rg, (l15 + 16 * cf) * 2, 256)) =
                    f2bf(yy[cf][rg]);
        }
        __syncthreads();   // ebuf overlay reads done before next layer's q01/k01 writes
    } // layers

    // ---------------- pool over the 128 tokens -----------------------------
    #pragma unroll
    for (int cf = 0; cf < 8; ++cf) {
        float s = hx[cf][0] + hx[cf][1] + hx[cf][2] + hx[cf][3];
        s += __shfl_xor(s, 16); s += __shfl_xor(s, 32);
        if (g == 0) pool_s[w * 128 + l15 + 16 * cf] = s;
    }
    __syncthreads();
    if (tid < 128) {
        float s = 0.f;
        #pragma unroll
        for (int ww = 0; ww < 8; ++ww) s += pool_s[ww * 128 + tid];
        pooled[b * HID + tid] = s * (1.f / 128.f);
    }
}

// ============================================================
// final mean over neighbors + prediction head
// ============================================================
__global__ void final_pred(const float* __restrict__ pooled,
                           const float* __restrict__ w1, const float* __restrict__ b1,
                           const float* __restrict__ w2, const float* __restrict__ b2,
                           float* __restrict__ out)
{
    __shared__ float part[4][HID];
    __shared__ float fin[HID];
    __shared__ float hm[HID];
    const int tid = threadIdx.x;           // 512
    const int f = tid & 127, q = tid >> 7;
    float s = 0.f;
    for (int bb = q * 256; bb < (q + 1) * 256; ++bb) s += pooled[bb * HID + f];
    part[q][f] = s;
    __syncthreads();
    if (tid < HID) {
        fin[tid] = (part[0][tid] + part[1][tid] + part[2][tid] + part[3][tid])
                   * (1.f / (float)D_N);
    }
    __syncthreads();
    if (tid < HID) {
        float a = b1[tid];
        for (int k = 0; k < HID; ++k) a += fin[k] * w1[tid * HID + k];
        hm[tid] = fmaxf(a, 0.f) * w2[tid];
    }
    __syncthreads();
    if (tid == 0) {
        float z = 0.f;
        for (int j = 0; j < HID; ++j) z += hm[j];
        z += b2[0];
        out[0] = 1.f / (1.f + __expf(-z));
    }
}

// ============================================================
// launch
// ============================================================
extern "C" void kernel_launch(void* const* d_in, const int* in_sizes, int n_in,
                              void* d_out, int out_size, void* d_ws, size_t ws_size,
                              hipStream_t stream)
{
    (void)in_sizes; (void)n_in; (void)out_size; (void)ws_size;

    const int*   tgt   = (const int*)  d_in[0];
    const int*   eidx  = (const int*)  d_in[2];
    const float* eattr = (const float*)d_in[3];
    const float* ftm   = (const float*)d_in[4];
    const float* projw = (const float*)d_in[5];
    const float* projb = (const float*)d_in[6];
    const float* aiw   = (const float*)d_in[7];
    const float* aib   = (const float*)d_in[8];
    const float* aow   = (const float*)d_in[9];
    const float* aob   = (const float*)d_in[10];
    const float* l1g   = (const float*)d_in[11];
    const float* l1b   = (const float*)d_in[12];
    const float* f1w   = (const float*)d_in[13];
    const float* f1b   = (const float*)d_in[14];
    const float* f2w   = (const float*)d_in[15];
    const float* f2b   = (const float*)d_in[16];
    const float* l2g   = (const float*)d_in[17];
    const float* l2b   = (const float*)d_in[18];
    const float* pw1   = (const float*)d_in[19];
    const float* pb1   = (const float*)d_in[20];
    const float* pw2   = (const float*)d_in[21];
    const float* pb2   = (const float*)d_in[22];

    char* ws = (char*)d_ws;
    int*   order  = (int*)  (ws + OFF_ORDER);
    int*   key    = (int*)  (ws + OFF_KEY);
    int*   slot   = (int*)  (ws + OFF_SLOT);
    int*   hist   = (int*)  (ws + OFF_HIST);
    int*   tot    = (int*)  (ws + OFF_TOT);
    float* pooled = (float*)(ws + OFF_POOL);
    short* wbf    = (short*)(ws + OFF_WBF);

    init_cvt     <<<dim3(1024), dim3(256),  0, stream>>>(slot, hist,
                                                         projw, aiw, aow, f1w, f2w, wbf);
    find_neigh   <<<dim3(1),    dim3(1024), 0, stream>>>(eidx, tgt, slot);
    compute_key  <<<dim3(512),  dim3(256),  0, stream>>>(eidx, tgt, slot, key);
    hist_build   <<<dim3(2),    dim3(256),  0, stream>>>(key, hist);
    scan_pass1   <<<dim3(9),    dim3(256),  0, stream>>>(hist, tot);
    scan_pass2   <<<dim3(1),    dim3(1024), 0, stream>>>(tot);
    scan_pass3   <<<dim3(513),  dim3(256),  0, stream>>>(hist, tot);
    scatter_order<<<dim3(2),    dim3(256),  0, stream>>>(key, hist, order);

    fused_mfma<<<dim3(D_N), dim3(512), 0, stream>>>(
        eattr, ftm,
        wbf + WP_OFF, projb,
        wbf + WI_OFF, aib,
        wbf + WO_OFF, aob,
        l1g, l1b,
        wbf + W1_OFF, f1b,
        wbf + W2_OFF, f2b,
        l2g, l2b,
        order, pooled);

    final_pred<<<dim3(1), dim3(512), 0, stream>>>(pooled, pw1, pb1, pw2, pb2, (float*)d_out);
}

// Round 6
// 466.230 us; speedup vs baseline: 1.7230x; 1.7230x over previous
//
#include <hip/hip_runtime.h>
#include <cstdint>
#include <cstddef>

// ---------------- problem constants ----------------
#define D_N     1024
#define K_S     128
#define EDIM    384
#define HID     128
#define NHEAD   4
#define HDIM    32
#define FFD     128
#define NLAYER  2
#define ETOT    (D_N * K_S)
#define NNODES  200000
#define NBINS   (2 * D_N + 2)
#define NCH     1024
#define CHL     (ETOT / NCH)    // 128

// ---------------- workspace layout (bytes) ----------------
#define OFF_ORDER 0u
#define OFF_KEY   0x080000u
#define OFF_SLOT  0x100000u
#define OFF_HIST  0x200000u                 // 2050*1024*4 = 8,396,800
#define OFF_TOT   0xA02000u
#define OFF_WBF   0xA08000u                 // 491,520 B
#define OFF_POOL  0xA80000u                 // 512 KB
#define WP_OFF 0
#define WI_OFF 49152
#define WO_OFF 147456
#define W1_OFF 180224
#define W2_OFF 212992
#define WTOT   245760

typedef __attribute__((ext_vector_type(8))) short  bf16x8;
typedef __attribute__((ext_vector_type(4))) short  short4v;
typedef __attribute__((ext_vector_type(4))) float  f32x4;

__device__ __forceinline__ short f2bf(float f) {
    union { float f; unsigned u; } v; v.f = f;
    unsigned r = v.u + 0x7fffu + ((v.u >> 16) & 1u);
    return (short)(r >> 16);
}
__device__ __forceinline__ int swz_off(int r, int byteInRow, int strideBytes) {
    return (r * strideBytes + byteInRow) ^ ((r & 7) << 4);
}

// ============================================================
// preprocessing
// ============================================================
__global__ void init_cvt(int* __restrict__ slot, int* __restrict__ hist,
                         const float* __restrict__ p0, const float* __restrict__ p1,
                         const float* __restrict__ p2, const float* __restrict__ p3,
                         const float* __restrict__ p4, short* __restrict__ wbf)
{
    int idx = blockIdx.x * blockDim.x + threadIdx.x;
    int stride = gridDim.x * blockDim.x;
    for (int i = idx; i < NBINS * NCH; i += stride) hist[i] = 0;
    for (int i = idx; i < NNODES; i += stride) slot[i] = D_N;
    int i = idx * 8;
    if (i < WTOT) {
        const float* s;
        if      (i < WI_OFF) s = p0 + i;
        else if (i < WO_OFF) s = p1 + (i - WI_OFF);
        else if (i < W1_OFF) s = p2 + (i - WO_OFF);
        else if (i < W2_OFF) s = p3 + (i - W1_OFF);
        else                 s = p4 + (i - W2_OFF);
        float4 a = *(const float4*)s;
        float4 b = *(const float4*)(s + 4);
        bf16x8 o;
        o[0] = f2bf(a.x); o[1] = f2bf(a.y); o[2] = f2bf(a.z); o[3] = f2bf(a.w);
        o[4] = f2bf(b.x); o[5] = f2bf(b.y); o[6] = f2bf(b.z); o[7] = f2bf(b.w);
        *(bf16x8*)(wbf + i) = o;
    }
}

__global__ void find_neigh(const int* __restrict__ eidx,
                           const int* __restrict__ tgt_idx,
                           int* __restrict__ slot)
{
    __shared__ int wtot[16];
    __shared__ int wbase_s[16];
    __shared__ int neigh[D_N];
    const int tid  = threadIdx.x;          // 1024
    const int lane = tid & 63;
    const int wv   = tid >> 6;
    const int tgt  = tgt_idx[0];
    const int* src = eidx;
    const int* dst = eidx + ETOT;
    const int epc  = ETOT / 1024;          // 128
    const int e0   = tid * epc;

    int c = 0;
    const int4* s4 = (const int4*)(src + e0);
    #pragma unroll 8
    for (int i = 0; i < epc / 4; ++i) {
        int4 v = s4[i];
        c += (v.x == tgt) + (v.y == tgt) + (v.z == tgt) + (v.w == tgt);
    }
    int incl = c;
    #pragma unroll
    for (int d = 1; d < 64; d <<= 1) {
        int t = __shfl_up(incl, d, 64);
        if (lane >= d) incl += t;
    }
    if (lane == 63) wtot[wv] = incl;
    __syncthreads();
    if (tid < 16) {
        int s = 0;
        for (int j = 0; j < tid; ++j) s += wtot[j];
        wbase_s[tid] = s;
    }
    __syncthreads();
    int r = wbase_s[wv] + incl - c;
    for (int e = e0; e < e0 + epc; ++e) {
        if (src[e] == tgt) { if (r < D_N) neigh[r] = dst[e]; ++r; }
    }
    __syncthreads();
    int total = wbase_s[15] + wtot[15];
    if (tid < total && tid < D_N) slot[neigh[tid]] = tid;
}

__global__ void compute_key(const int* __restrict__ eidx,
                            const int* __restrict__ tgt_idx,
                            const int* __restrict__ slot,
                            int* __restrict__ key)
{
    int e = blockIdx.x * 256 + threadIdx.x;
    if (e >= ETOT) return;
    int tgt = tgt_idx[0];
    key[e] = slot[eidx[ETOT + e]] * 2 + ((eidx[e] != tgt) ? 1 : 0);
}

__global__ void hist_build(const int* __restrict__ key, int* __restrict__ hist)
{
    const int c = blockIdx.x * 256 + threadIdx.x;
    if (c >= NCH) return;
    const int4* kp = (const int4*)(key + c * CHL);
    int cur = -1, run = 0;
    for (int i = 0; i < CHL / 4; ++i) {
        int4 k4 = kp[i];
        #pragma unroll
        for (int j = 0; j < 4; ++j) {
            int k = (j == 0) ? k4.x : (j == 1) ? k4.y : (j == 2) ? k4.z : k4.w;
            if (k == cur) { ++run; }
            else {
                if (run) hist[cur * NCH + c] += run;
                cur = k; run = 1;
            }
        }
    }
    if (run) hist[cur * NCH + c] += run;
}

__global__ void scan_pass1(const int* __restrict__ hist, int* __restrict__ tot)
{
    int b = blockIdx.x * 256 + threadIdx.x;
    if (b >= NBINS) return;
    const int4* h = (const int4*)(hist + b * NCH);
    int s = 0;
    #pragma unroll 4
    for (int c = 0; c < NCH / 4; ++c) { int4 v = h[c]; s += v.x + v.y + v.z + v.w; }
    tot[b] = s;
}

#define SCN 2176
__global__ void scan_pass2(int* __restrict__ tot)
{
    __shared__ int A[SCN];
    __shared__ int B[SCN];
    const int tid = threadIdx.x;   // 1024
    for (int i = tid; i < SCN; i += 1024) A[i] = (i < NBINS) ? tot[i] : 0;
    __syncthreads();
    int* cur = A; int* nxt = B;
    for (int s = 1; s < SCN; s <<= 1) {
        for (int i = tid; i < SCN; i += 1024) nxt[i] = (i >= s) ? cur[i] + cur[i - s] : cur[i];
        __syncthreads();
        int* t = cur; cur = nxt; nxt = t;
    }
    for (int i = tid; i < NBINS; i += 1024) tot[i] = (i == 0) ? 0 : cur[i - 1];
}

// one wave per bin: lane owns 16 consecutive chunk-counters
__global__ void scan_pass3(int* __restrict__ hist, const int* __restrict__ base)
{
    const int wvg  = (blockIdx.x * blockDim.x + threadIdx.x) >> 6;
    const int lane = threadIdx.x & 63;
    if (wvg >= NBINS) return;
    int* h = hist + wvg * NCH + lane * 16;
    int4 a0 = ((int4*)h)[0], a1 = ((int4*)h)[1], a2 = ((int4*)h)[2], a3 = ((int4*)h)[3];
    int ls = a0.x + a0.y + a0.z + a0.w + a1.x + a1.y + a1.z + a1.w
           + a2.x + a2.y + a2.z + a2.w + a3.x + a3.y + a3.z + a3.w;
    int incl = ls;
    #pragma unroll
    for (int d = 1; d < 64; d <<= 1) {
        int t = __shfl_up(incl, d, 64);
        if (lane >= d) incl += t;
    }
    int run = base[wvg] + incl - ls;
    int4 o;
    o.x = run; run += a0.x; o.y = run; run += a0.y;
    o.z = run; run += a0.z; o.w = run; run += a0.w; ((int4*)h)[0] = o;
    o.x = run; run += a1.x; o.y = run; run += a1.y;
    o.z = run; run += a1.z; o.w = run; run += a1.w; ((int4*)h)[1] = o;
    o.x = run; run += a2.x; o.y = run; run += a2.y;
    o.z = run; run += a2.z; o.w = run; run += a2.w; ((int4*)h)[2] = o;
    o.x = run; run += a3.x; o.y = run; run += a3.y;
    o.z = run; run += a3.z; o.w = run; run += a3.w; ((int4*)h)[3] = o;
}

__global__ void scatter_order(const int* __restrict__ key,
                              int* __restrict__ hist,
                              int* __restrict__ order)
{
    const int c = blockIdx.x * 256 + threadIdx.x;
    if (c >= NCH) return;
    const int e0 = c * CHL;
    const int4* kp = (const int4*)(key + e0);
    int cur = -1, pos = 0;
    for (int i = 0; i < CHL / 4; ++i) {
        int4 k4 = kp[i];
        #pragma unroll
        for (int j = 0; j < 4; ++j) {
            int k = (j == 0) ? k4.x : (j == 1) ? k4.y : (j == 2) ? k4.z : k4.w;
            if (k != cur) {
                if (cur >= 0) hist[cur * NCH + c] = pos;
                cur = k;
                pos = hist[k * NCH + c];
            }
            if (pos >= 0 && pos < ETOT) order[pos] = e0 + i * 4 + j;
            ++pos;
        }
    }
    if (cur >= 0) hist[cur * NCH + c] = pos;
}

// ============================================================
// MFMA helpers
// ============================================================
template<int CF, int KC, typename GetB>
__device__ __forceinline__ void gemm1(f32x4 (&acc)[CF],
    const char* aB, int aRow0, int aStride, int aColOff, int l15, int g, GetB getB)
{
    #pragma unroll
    for (int kc = 0; kc < KC; ++kc) {
        bf16x8 a = *(const bf16x8*)(aB +
            swz_off(aRow0 + l15, aColOff + kc * 64 + g * 16, aStride));
        #pragma unroll
        for (int cf = 0; cf < CF; ++cf)
            acc[cf] = __builtin_amdgcn_mfma_f32_16x16x32_bf16(a, getB(cf, kc), acc[cf], 0, 0, 0);
    }
}

// stage a bf16 matrix (row-major, ROWB bytes/row) into swizzled LDS (512 thr)
template<int ROWB>
__device__ __forceinline__ void stage_w(const char* __restrict__ gsrc, char* ldst,
                                        int nbytes, int tid)
{
    #pragma unroll 4
    for (int u = tid * 16; u < nbytes; u += 512 * 16) {
        int row = u / ROWB;
        int in  = u - row * ROWB;
        *(bf16x8*)(ldst + swz_off(row, in, ROWB)) = *(const bf16x8*)(gsrc + u);
    }
}

__device__ __forceinline__ void layer_norm1(f32x4 (&x)[8],
    const float* __restrict__ gg, const float* __restrict__ bb, int l15)
{
    float gv[8], bv[8];
    #pragma unroll
    for (int cf = 0; cf < 8; ++cf) { gv[cf] = gg[l15 + 16 * cf]; bv[cf] = bb[l15 + 16 * cf]; }
    #pragma unroll
    for (int rg = 0; rg < 4; ++rg) {
        float s = 0.f;
        #pragma unroll
        for (int cf = 0; cf < 8; ++cf) s += x[cf][rg];
        s += __shfl_xor(s, 1); s += __shfl_xor(s, 2);
        s += __shfl_xor(s, 4); s += __shfl_xor(s, 8);
        float mean = s * (1.f / 128.f);
        float v = 0.f;
        #pragma unroll
        for (int cf = 0; cf < 8; ++cf) { float d = x[cf][rg] - mean; v += d * d; }
        v += __shfl_xor(v, 1); v += __shfl_xor(v, 2);
        v += __shfl_xor(v, 4); v += __shfl_xor(v, 8);
        float rs = rsqrtf(v * (1.f / 128.f) + 1e-5f);
        #pragma unroll
        for (int cf = 0; cf < 8; ++cf)
            x[cf][rg] = (x[cf][rg] - mean) * rs * gv[cf] + bv[cf];
    }
}

// write hx fragments into a [128][256B] swizzled bf16 buffer (own rows)
__device__ __forceinline__ void write_hbf(const f32x4 (&x)[8], char* hbf_n,
                                          int l15, int g, int row0)
{
    #pragma unroll
    for (int cf = 0; cf < 8; ++cf)
        #pragma unroll
        for (int rg = 0; rg < 4; ++rg)
            *(short*)(hbf_n + swz_off(row0 + g * 4 + rg, (l15 + 16 * cf) * 2, 256)) =
                f2bf(x[cf][rg]);
}

// ---- proj for one neighbor (all wave-local; ebuf == hbf_n) ----
__device__ __forceinline__ void proj_one(f32x4 (&hx)[8], char* hbf_n,
    const char* wp_lds, const float* __restrict__ edge_attrs,
    const int* __restrict__ order, const float* __restrict__ projb,
    const float* __restrict__ ftm, int nIdx, int l, int l15, int g, int row0)
{
    #pragma unroll
    for (int cf = 0; cf < 8; ++cf) {
        float bs = projb[l15 + 16 * cf];
        hx[cf] = (f32x4){bs, bs, bs, bs};
    }
    const int r_off = l >> 2;
    const int coff  = (l & 3) * 32;
    const int row   = row0 + r_off;
    const float* arow = edge_attrs + (size_t)order[nIdx * K_S + row] * EDIM;

    float4 v[8];
    #pragma unroll
    for (int j = 0; j < 8; ++j) v[j] = *(const float4*)(arow + coff + j * 4);

    #pragma unroll
    for (int ch = 0; ch < 3; ++ch) {
        #pragma unroll
        for (int j = 0; j < 4; ++j) {
            float4 a = v[2 * j], c = v[2 * j + 1];
            bf16x8 pk;
            pk[0] = f2bf(a.x); pk[1] = f2bf(a.y); pk[2] = f2bf(a.z); pk[3] = f2bf(a.w);
            pk[4] = f2bf(c.x); pk[5] = f2bf(c.y); pk[6] = f2bf(c.z); pk[7] = f2bf(c.w);
            *(bf16x8*)(hbf_n + swz_off(row, coff * 2 + j * 16, 256)) = pk;
        }
        if (ch < 2) {
            #pragma unroll
            for (int j = 0; j < 8; ++j)
                v[j] = *(const float4*)(arow + (ch + 1) * 128 + coff + j * 4);
        }
        gemm1<8, 4>(hx, hbf_n, row0, 256, 0, l15, g,
            [&](int cf, int kc) {
                return *(const bf16x8*)(wp_lds +
                    swz_off(l15 + 16 * cf, ch * 256 + kc * 64 + g * 16, 768));
            });
    }
    if (row0 == 0 && g == 0) {
        #pragma unroll
        for (int cf = 0; cf < 8; ++cf) hx[cf][0] += ftm[l15 + 16 * cf];
    }
    write_hbf(hx, hbf_n, l15, g, row0);
}

// ---- QKV for one neighbor / one head (B = staged Wqkv head in LDS) ----
__device__ __forceinline__ void qkv_one(const char* hbf_n,
    char* qb, char* kb, char* vb, const char* wh_lds,
    const float* __restrict__ bI, int hd, int l15, int g, int row0)
{
    f32x4 acc[6];
    #pragma unroll
    for (int cf = 0; cf < 6; ++cf) {
        float bs = bI[(cf >> 1) * HID + hd * HDIM + l15 + 16 * (cf & 1)];
        acc[cf] = (f32x4){bs, bs, bs, bs};
    }
    gemm1<6, 4>(acc, hbf_n, row0, 256, 0, l15, g,
        [&](int cf, int kc) {
            int rw = (cf >> 1) * 32 + l15 + 16 * (cf & 1);
            return *(const bf16x8*)(wh_lds + swz_off(rw, kc * 64 + g * 16, 256));
        });
    #pragma unroll
    for (int cf = 0; cf < 2; ++cf) {
        int dcol = (l15 + 16 * cf) * 2;
        #pragma unroll
        for (int rg = 0; rg < 4; ++rg) {
            int row = row0 + g * 4 + rg;
            *(short*)(qb + swz_off(row, dcol, 64)) = f2bf(acc[cf][rg]);
            *(short*)(kb + swz_off(row, dcol, 64)) = f2bf(acc[2 + cf][rg]);
        }
        short4v pv;
        pv[0] = f2bf(acc[4 + cf][0]); pv[1] = f2bf(acc[4 + cf][1]);
        pv[2] = f2bf(acc[4 + cf][2]); pv[3] = f2bf(acc[4 + cf][3]);
        *(short4v*)(vb + swz_off(l15 + 16 * cf, (row0 + g * 4) * 2, 256)) = pv;
    }
}

// ---- attention for one neighbor / one head; accumulates out-proj into hx ----
__device__ __forceinline__ void attn_one(char* qb, const char* kb, const char* vb,
    const short* __restrict__ WOl, f32x4 (&hx)[8], int hd, int l15, int g, int row0)
{
    // S = Q K^T
    f32x4 sc[8];
    #pragma unroll
    for (int cf = 0; cf < 8; ++cf) sc[cf] = (f32x4){0.f, 0.f, 0.f, 0.f};
    gemm1<8, 1>(sc, qb, row0, 64, 0, l15, g,
        [&](int cf, int kc) {
            (void)kc;
            return *(const bf16x8*)(kb + swz_off(l15 + 16 * cf, g * 16, 64));
        });
    // softmax
    const float SC_ = 0.17677669529663687f;   // 1/sqrt(32)
    float inv_s[4];
    #pragma unroll
    for (int rg = 0; rg < 4; ++rg) {
        float mx = -1e30f;
        #pragma unroll
        for (int cf = 0; cf < 8; ++cf) {
            sc[cf][rg] *= SC_;
            mx = fmaxf(mx, sc[cf][rg]);
        }
        mx = fmaxf(mx, __shfl_xor(mx, 1)); mx = fmaxf(mx, __shfl_xor(mx, 2));
        mx = fmaxf(mx, __shfl_xor(mx, 4)); mx = fmaxf(mx, __shfl_xor(mx, 8));
        float sum = 0.f;
        #pragma unroll
        for (int cf = 0; cf < 8; ++cf) {
            float e = __expf(sc[cf][rg] - mx);
            sc[cf][rg] = e; sum += e;
        }
        sum += __shfl_xor(sum, 1); sum += __shfl_xor(sum, 2);
        sum += __shfl_xor(sum, 4); sum += __shfl_xor(sum, 8);
        inv_s[rg] = 1.f / sum;
    }
    // O = P V via P-chunks overlaying the (consumed, wave-local) q rows
    f32x4 ov[2];
    ov[0] = (f32x4){0.f, 0.f, 0.f, 0.f};
    ov[1] = (f32x4){0.f, 0.f, 0.f, 0.f};
    #pragma unroll
    for (int cc = 0; cc < 4; ++cc) {
        #pragma unroll
        for (int q = 0; q < 2; ++q) {
            int cfi = 2 * cc + q;
            #pragma unroll
            for (int rg = 0; rg < 4; ++rg)
                *(short*)(qb + swz_off(row0 + g * 4 + rg, (l15 + 16 * q) * 2, 64)) =
                    f2bf(sc[cfi][rg] * inv_s[rg]);
        }
        gemm1<2, 1>(ov, qb, row0, 64, 0, l15, g,
            [&](int cf, int kc) {
                (void)kc;
                return *(const bf16x8*)(vb + swz_off(l15 + 16 * cf, cc * 64 + g * 16, 256));
            });
    }
    // O_head -> qb (own rows), out-proj accumulate (B from L2, broadcast)
    #pragma unroll
    for (int cf = 0; cf < 2; ++cf)
        #pragma unroll
        for (int rg = 0; rg < 4; ++rg)
            *(short*)(qb + swz_off(row0 + g * 4 + rg, (l15 + 16 * cf) * 2, 64)) =
                f2bf(ov[cf][rg]);
    gemm1<8, 1>(hx, qb, row0, 64, 0, l15, g,
        [&](int cf, int kc) {
            (void)kc;
            return *(const bf16x8*)(WOl +
                (size_t)(l15 + 16 * cf) * HID + hd * HDIM + g * 8);
        });
}

// ============================================================
// fused transformer: 1 block = 2 neighbors; 512 thr = 8 waves x 16 rows each.
// LDS 160 KB: hbfA 32 | hbfB 32 | Wbuf 48 | qkv 48. Weights staged in LDS,
// staging overlapped under attention / FF compute. Grid 512 -> 2 generations.
// ============================================================
#define LDS_TOTAL 163840
__global__ __launch_bounds__(512, 2) void fused_mfma(
    const float* __restrict__ edge_attrs,
    const float* __restrict__ ftm,
    const short* __restrict__ wP, const float* __restrict__ projb,
    const short* __restrict__ wI, const float* __restrict__ aib,
    const short* __restrict__ wO, const float* __restrict__ aob,
    const float* __restrict__ l1g, const float* __restrict__ l1b,
    const short* __restrict__ w1, const float* __restrict__ f1b,
    const short* __restrict__ w2, const float* __restrict__ f2b,
    const float* __restrict__ l2g, const float* __restrict__ l2b,
    const int*   __restrict__ order,
    float*       __restrict__ pooled)
{
    __shared__ __align__(16) char sm[LDS_TOTAL];
    char* hbfA = sm;                        // 32 KB [128][256B] swz (ebufA in proj)
    char* hbfB = sm + 32768;                // 32 KB
    char* wb   = sm + 65536;                // 48 KB: Wqkv-head(24K) / W1(32K)+W2h0(16K)
    char* qkv  = sm + 114688;               // 48 KB
    char* qA   = qkv;                       //  8 KB [128][64B]
    char* kA   = qkv + 8192;                //  8 KB
    char* vTA  = qkv + 16384;               //  8 KB [32][256B]
    char* qB   = qkv + 24576;
    char* kB   = qkv + 32768;
    char* vTB  = qkv + 40960;
    char* ffb  = qkv;                       // 32 KB [128][256B] (FF phase overlay)
    char* w2h1 = qkv + 32768;               // 16 KB (FF phase overlay)
    // proj: wP staged contiguously across wb..end (96 KB)

    const int tid  = threadIdx.x;
    const int w    = tid >> 6;
    const int l    = tid & 63;
    const int l15  = l & 15;
    const int g    = l >> 4;
    const int row0 = 16 * w;
    const int nA   = 2 * blockIdx.x;
    const int nB   = 2 * blockIdx.x + 1;

    f32x4 hxA[8], hxB[8];

    // ---------------- proj ------------------------------------------------
    stage_w<768>((const char*)wP, wb, 98304, tid);
    __syncthreads();
    proj_one(hxA, hbfA, wb, edge_attrs, order, projb, ftm, nA, l, l15, g, row0);
    proj_one(hxB, hbfB, wb, edge_attrs, order, projb, ftm, nB, l, l15, g, row0);
    __syncthreads();   // wP dead -> wb/qkv free

    // ---------------- transformer layers ----------------------------------
    for (int ly = 0; ly < NLAYER; ++ly) {
        const short* WIl = wI + (size_t)ly * 3 * HID * HID;
        const float* bI  = aib + ly * 3 * HID;
        const short* WOl = wO + (size_t)ly * HID * HID;
        const float* bO  = aob + ly * HID;
        const short* W1l = w1 + (size_t)ly * FFD * HID;
        const float* b1  = f1b + ly * FFD;
        const short* W2l = w2 + (size_t)ly * HID * FFD;
        const float* b2v = f2b + ly * HID;

        // stage Wqkv head 0 (exposed, small); fold bO under it
        #pragma unroll
        for (int sec = 0; sec < 3; ++sec)
            stage_w<256>((const char*)(WIl + (size_t)(sec * HID) * HID),
                         wb + sec * 8192, 8192, tid);
        #pragma unroll
        for (int cf = 0; cf < 8; ++cf) {
            float bs = bO[l15 + 16 * cf];
            #pragma unroll
            for (int rg = 0; rg < 4; ++rg) { hxA[cf][rg] += bs; hxB[cf][rg] += bs; }
        }
        __syncthreads();

        for (int hd = 0; hd < NHEAD; ++hd) {
            // ---- QKV phase (Wh visible) ----
            qkv_one(hbfA, qA, kA, vTA, wb, bI, hd, l15, g, row0);
            qkv_one(hbfB, qB, kB, vTB, wb, bI, hd, l15, g, row0);
            __syncthreads();   // qkv visible; wb dead

            // ---- attn phase; stage next weights into wb under it ----
            if (hd < NHEAD - 1) {
                #pragma unroll
                for (int sec = 0; sec < 3; ++sec)
                    stage_w<256>((const char*)(WIl +
                        (size_t)(sec * HID + (hd + 1) * HDIM) * HID),
                        wb + sec * 8192, 8192, tid);
            } else {
                stage_w<256>((const char*)W1l, wb, 32768, tid);          // W1 full
                stage_w<256>((const char*)W2l, wb + 32768, 16384, tid);  // W2 rows 0..63
            }
            attn_one(qA, kA, vTA, WOl, hxA, hd, l15, g, row0);
            attn_one(qB, kB, vTB, WOl, hxB, hd, l15, g, row0);
            __syncthreads();
        }

        // ---- FF phase alpha: LN1 both, FF1-A, FF2h0-A; stage W2h1 ----
        stage_w<256>((const char*)W2l + 16384, w2h1, 16384, tid);        // W2 rows 64..127
        layer_norm1(hxA, l1g + ly * HID, l1b + ly * HID, l15);
        layer_norm1(hxB, l1g + ly * HID, l1b + ly * HID, l15);
        write_hbf(hxA, hbfA, l15, g, row0);
        write_hbf(hxB, hbfB, l15, g, row0);

        f32x4 ffA[8];
        #pragma unroll
        for (int cf = 0; cf < 8; ++cf) {
            float bs = b1[l15 + 16 * cf];
            ffA[cf] = (f32x4){bs, bs, bs, bs};
        }
        gemm1<8, 4>(ffA, hbfA, row0, 256, 0, l15, g,
            [&](int cf, int kc) {
                return *(const bf16x8*)(wb + swz_off(l15 + 16 * cf, kc * 64 + g * 16, 256));
            });
        #pragma unroll
        for (int cf = 0; cf < 8; ++cf)
            #pragma unroll
            for (int rg = 0; rg < 4; ++rg)
                *(short*)(ffb + swz_off(row0 + g * 4 + rg, (l15 + 16 * cf) * 2, 256)) =
                    f2bf(fmaxf(ffA[cf][rg], 0.f));

        f32x4 yAlo[4];
        #pragma unroll
        for (int cf = 0; cf < 4; ++cf) {
            float bs = b2v[l15 + 16 * cf];
            yAlo[cf] = (f32x4){bs, bs, bs, bs};
        }
        gemm1<4, 4>(yAlo, ffb, row0, 256, 0, l15, g,
            [&](int cf, int kc) {
                return *(const bf16x8*)(wb + 32768 +
                    swz_off(l15 + 16 * cf, kc * 64 + g * 16, 256));
            });
        __syncthreads();   // w2h1 visible

        // ---- FF phase beta: finish A; full FF for B (all wave-local) ----
        f32x4 yAhi[4];
        #pragma unroll
        for (int cf = 0; cf < 4; ++cf) {
            float bs = b2v[64 + l15 + 16 * cf];
            yAhi[cf] = (f32x4){bs, bs, bs, bs};
        }
        gemm1<4, 4>(yAhi, ffb, row0, 256, 0, l15, g,
            [&](int cf, int kc) {
                return *(const bf16x8*)(w2h1 +
                    swz_off(l15 + 16 * cf, kc * 64 + g * 16, 256));
            });
        {
            f32x4 x[8];
            #pragma unroll
            for (int cf = 0; cf < 4; ++cf) { x[cf] = yAlo[cf] + hxA[cf]; x[4 + cf] = yAhi[cf] + hxA[4 + cf]; }
            layer_norm1(x, l2g + ly * HID, l2b + ly * HID, l15);
            #pragma unroll
            for (int cf = 0; cf < 8; ++cf) hxA[cf] = x[cf];
            write_hbf(hxA, hbfA, l15, g, row0);
        }
        // B: FF1 -> ffb (overwrite own rows; prior reads were own-wave) -> FF2
        f32x4 ffB[8];
        #pragma unroll
        for (int cf = 0; cf < 8; ++cf) {
            float bs = b1[l15 + 16 * cf];
            ffB[cf] = (f32x4){bs, bs, bs, bs};
        }
        gemm1<8, 4>(ffB, hbfB, row0, 256, 0, l15, g,
            [&](int cf, int kc) {
                return *(const bf16x8*)(wb + swz_off(l15 + 16 * cf, kc * 64 + g * 16, 256));
            });
        #pragma unroll
        for (int cf = 0; cf < 8; ++cf)
            #pragma unroll
            for (int rg = 0; rg < 4; ++rg)
                *(short*)(ffb + swz_off(row0 + g * 4 + rg, (l15 + 16 * cf) * 2, 256)) =
                    f2bf(fmaxf(ffB[cf][rg], 0.f));
        f32x4 yBlo[4], yBhi[4];
        #pragma unroll
        for (int cf = 0; cf < 4; ++cf) {
            float bs0 = b2v[l15 + 16 * cf];
            float bs1 = b2v[64 + l15 + 16 * cf];
            yBlo[cf] = (f32x4){bs0, bs0, bs0, bs0};
            yBhi[cf] = (f32x4){bs1, bs1, bs1, bs1};
        }
        gemm1<4, 4>(yBlo, ffb, row0, 256, 0, l15, g,
            [&](int cf, int kc) {
                return *(const bf16x8*)(wb + 32768 +
                    swz_off(l15 + 16 * cf, kc * 64 + g * 16, 256));
            });
        gemm1<4, 4>(yBhi, ffb, row0, 256, 0, l15, g,
            [&](int cf, int kc) {
                return *(const bf16x8*)(w2h1 +
                    swz_off(l15 + 16 * cf, kc * 64 + g * 16, 256));
            });
        {
            f32x4 x[8];
            #pragma unroll
            for (int cf = 0; cf < 4; ++cf) { x[cf] = yBlo[cf] + hxB[cf]; x[4 + cf] = yBhi[cf] + hxB[4 + cf]; }
            layer_norm1(x, l2g + ly * HID, l2b + ly * HID, l15);
            #pragma unroll
            for (int cf = 0; cf < 8; ++cf) hxB[cf] = x[cf];
            write_hbf(hxB, hbfB, l15, g, row0);
        }
        __syncthreads();   // end of layer: wb/qkv free
    } // layers

    // ---------------- pool (both neighbors) --------------------------------
    float* poolA = (float*)wb;              // [8][128]
    float* poolB = (float*)(wb + 4096);
    #pragma unroll
    for (int cf = 0; cf < 8; ++cf) {
        float sA = hxA[cf][0] + hxA[cf][1] + hxA[cf][2] + hxA[cf][3];
        float sB = hxB[cf][0] + hxB[cf][1] + hxB[cf][2] + hxB[cf][3];
        sA += __shfl_xor(sA, 16); sA += __shfl_xor(sA, 32);
        sB += __shfl_xor(sB, 16); sB += __shfl_xor(sB, 32);
        if (g == 0) {
            poolA[w * 128 + l15 + 16 * cf] = sA;
            poolB[w * 128 + l15 + 16 * cf] = sB;
        }
    }
    __syncthreads();
    if (tid < 128) {
        float s = 0.f;
        #pragma unroll
        for (int ww = 0; ww < 8; ++ww) s += poolA[ww * 128 + tid];
        pooled[nA * HID + tid] = s * (1.f / 128.f);
    } else if (tid < 256) {
        int f = tid - 128;
        float s = 0.f;
        #pragma unroll
        for (int ww = 0; ww < 8; ++ww) s += poolB[ww * 128 + f];
        pooled[nB * HID + f] = s * (1.f / 128.f);
    }
}

// ============================================================
// final mean over neighbors + prediction head
// ============================================================
__global__ void final_pred(const float* __restrict__ pooled,
                           const float* __restrict__ w1, const float* __restrict__ b1,
                           const float* __restrict__ w2, const float* __restrict__ b2,
                           float* __restrict__ out)
{
    __shared__ float part[4][HID];
    __shared__ float fin[HID];
    __shared__ float hm[HID];
    const int tid = threadIdx.x;           // 512
    const int f = tid & 127, q = tid >> 7;
    float s = 0.f;
    for (int bb = q * 256; bb < (q + 1) * 256; ++bb) s += pooled[bb * HID + f];
    part[q][f] = s;
    __syncthreads();
    if (tid < HID) {
        fin[tid] = (part[0][tid] + part[1][tid] + part[2][tid] + part[3][tid])
                   * (1.f / (float)D_N);
    }
    __syncthreads();
    if (tid < HID) {
        float a = b1[tid];
        for (int k = 0; k < HID; ++k) a += fin[k] * w1[tid * HID + k];
        hm[tid] = fmaxf(a, 0.f) * w2[tid];
    }
    __syncthreads();
    if (tid == 0) {
        float z = 0.f;
        for (int j = 0; j < HID; ++j) z += hm[j];
        z += b2[0];
        out[0] = 1.f / (1.f + __expf(-z));
    }
}

// ============================================================
// launch
// ============================================================
extern "C" void kernel_launch(void* const* d_in, const int* in_sizes, int n_in,
                              void* d_out, int out_size, void* d_ws, size_t ws_size,
                              hipStream_t stream)
{
    (void)in_sizes; (void)n_in; (void)out_size; (void)ws_size;

    const int*   tgt   = (const int*)  d_in[0];
    const int*   eidx  = (const int*)  d_in[2];
    const float* eattr = (const float*)d_in[3];
    const float* ftm   = (const float*)d_in[4];
    const float* projw = (const float*)d_in[5];
    const float* projb = (const float*)d_in[6];
    const float* aiw   = (const float*)d_in[7];
    const float* aib   = (const float*)d_in[8];
    const float* aow   = (const float*)d_in[9];
    const float* aob   = (const float*)d_in[10];
    const float* l1g   = (const float*)d_in[11];
    const float* l1b   = (const float*)d_in[12];
    const float* f1w   = (const float*)d_in[13];
    const float* f1b   = (const float*)d_in[14];
    const float* f2w   = (const float*)d_in[15];
    const float* f2b   = (const float*)d_in[16];
    const float* l2g   = (const float*)d_in[17];
    const float* l2b   = (const float*)d_in[18];
    const float* pw1   = (const float*)d_in[19];
    const float* pb1   = (const float*)d_in[20];
    const float* pw2   = (const float*)d_in[21];
    const float* pb2   = (const float*)d_in[22];

    char* ws = (char*)d_ws;
    int*   order  = (int*)  (ws + OFF_ORDER);
    int*   key    = (int*)  (ws + OFF_KEY);
    int*   slot   = (int*)  (ws + OFF_SLOT);
    int*   hist   = (int*)  (ws + OFF_HIST);
    int*   tot    = (int*)  (ws + OFF_TOT);
    float* pooled = (float*)(ws + OFF_POOL);
    short* wbf    = (short*)(ws + OFF_WBF);

    init_cvt     <<<dim3(2048), dim3(256),  0, stream>>>(slot, hist,
                                                         projw, aiw, aow, f1w, f2w, wbf);
    find_neigh   <<<dim3(1),    dim3(1024), 0, stream>>>(eidx, tgt, slot);
    compute_key  <<<dim3(512),  dim3(256),  0, stream>>>(eidx, tgt, slot, key);
    hist_build   <<<dim3(4),    dim3(256),  0, stream>>>(key, hist);
    scan_pass1   <<<dim3(9),    dim3(256),  0, stream>>>(hist, tot);
    scan_pass2   <<<dim3(1),    dim3(1024), 0, stream>>>(tot);
    scan_pass3   <<<dim3(513),  dim3(256),  0, stream>>>(hist, tot);
    scatter_order<<<dim3(4),    dim3(256),  0, stream>>>(key, hist, order);

    fused_mfma<<<dim3(D_N / 2), dim3(512), 0, stream>>>(
        eattr, ftm,
        wbf + WP_OFF, projb,
        wbf + WI_OFF, aib,
        wbf + WO_OFF, aob,
        l1g, l1b,
        wbf + W1_OFF, f1b,
        wbf + W2_OFF, f2b,
        l2g, l2b,
        order, pooled);

    final_pred<<<dim3(1), dim3(512), 0, stream>>>(pooled, pw1, pb1, pw2, pb2, (float*)d_out);
}